// Round 8
// baseline (192.392 us; speedup 1.0000x reference)
//
#include <hip/hip_runtime.h>

// BrewCnnLayer v7: fused, 128-thread block (2 waves) per image.
// R7 lesson: LDS pipe (shared per-CU, b128=12cyc) was the wall (~70us of the
// 106us). DS instr count is PER WAVE-INSTR regardless of dup lanes -> use few
// waves with multi-row strips for input-row reuse:
//   conv1: 2-row strips, 110 tasks on 2 waves, rolling weight-row registers.
//   conv2: 3-row strips, 60 tasks on wave 0 ONLY (wave 1 exits after conv1);
//          per ic: 49 DS feed 1350 FMA wave-instrs (ratio ~2x better than v6b).
// Weights/image/h1 all in LDS (R1/R5: s_load+ds lgkmcnt mixing stalls).
// fp32 vector math (no fp32 MFMA; bf16 flips ratio signs).
// out = [ h2 (b*3240) | rat1 (b*4840) | rat2 (b*3240) ]  (f32)

#define THREADS 128

__global__ __launch_bounds__(THREADS) void brewcnn_v7(
    const float* __restrict__ x,    // (nimg, 784)
    const float* __restrict__ Wa,   // (10, 49)
    const float* __restrict__ Wb,   // (10, 250)
    float* __restrict__ out,
    int nimg)
{
    __shared__ __align__(16) float s_x[784];        // 3136 B, row stride 28
    __shared__ __align__(16) float s_h[10 * 532];   // 21280 B: oc*532 + row*24 + col
    __shared__ __align__(16) float s_wa[560];       // 2240 B: [oc][ky][8] (k=7 pad 0)
    __shared__ __align__(16) float s_wb[2800];      // 11200 B: [oc][ic][28] (25..27 pad 0)
                                                    // total 37,856 B -> 4 blocks/CU
    const int img = blockIdx.x;
    const int tid = threadIdx.x;

    // ---- staging (full-coverage loops; v6 bug class audited) ----
    for (int i = tid; i < 196; i += THREADS)
        reinterpret_cast<float4*>(s_x)[i] =
            reinterpret_cast<const float4*>(x + img * 784)[i];
    for (int i = tid; i < 560; i += THREADS) {
        const int oc = i / 56, r = i - oc * 56, ky = r >> 3, k = r & 7;
        s_wa[i] = (k < 7) ? Wa[oc * 49 + ky * 7 + k] : 0.0f;
    }
    for (int i = tid; i < 2800; i += THREADS) {
        const int oc = i / 280, r = i - oc * 280, ic = r / 28, k = r - ic * 28;
        s_wb[i] = (k < 25) ? Wb[oc * 250 + ic * 25 + k] : 0.0f;
    }
    __syncthreads();

    const int h2_base = img * 3240;
    const int r1_base = nimg * 3240 + img * 4840;
    const int r2_base = nimg * 8080 + img * 3240;

    // ---- conv1: task = (rowpair g 0..10, oc 0..9), 110 tasks on 2 waves ----
    {
        const int t  = tid < 110 ? tid : 109;
        const int g  = t / 10;
        const int oc = t - g * 10;
        const int r0 = 2 * g;

        float acc[2][22];
#pragma unroll
        for (int o = 0; o < 2; ++o)
#pragma unroll
            for (int px = 0; px < 22; ++px) acc[o][px] = 0.0f;

        float wcur[7], wprev[7];
        float in[28];

        // ri = 0 (peeled): out row 0, ky = 0
        {
            const float4* rp = reinterpret_cast<const float4*>(s_x + r0 * 28);
#pragma unroll
            for (int j = 0; j < 7; ++j) {
                const float4 v = rp[j];
                in[4*j+0] = v.x; in[4*j+1] = v.y; in[4*j+2] = v.z; in[4*j+3] = v.w;
            }
            const float4* wp = reinterpret_cast<const float4*>(s_wa + oc * 56);
            const float4 a = wp[0], b = wp[1];
            wcur[0]=a.x; wcur[1]=a.y; wcur[2]=a.z; wcur[3]=a.w;
            wcur[4]=b.x; wcur[5]=b.y; wcur[6]=b.z;
#pragma unroll
            for (int kx = 0; kx < 7; ++kx)
#pragma unroll
                for (int px = 0; px < 22; ++px)
                    acc[0][px] = fmaf(in[px + kx], wcur[kx], acc[0][px]);
#pragma unroll
            for (int k = 0; k < 7; ++k) wprev[k] = wcur[k];
        }

#pragma unroll 1
        for (int ri = 1; ri <= 6; ++ri) {
            const float4* rp = reinterpret_cast<const float4*>(s_x + (r0 + ri) * 28);
#pragma unroll
            for (int j = 0; j < 7; ++j) {
                const float4 v = rp[j];
                in[4*j+0] = v.x; in[4*j+1] = v.y; in[4*j+2] = v.z; in[4*j+3] = v.w;
            }
            const float4* wp = reinterpret_cast<const float4*>(s_wa + oc * 56 + ri * 8);
            const float4 a = wp[0], b = wp[1];
            wcur[0]=a.x; wcur[1]=a.y; wcur[2]=a.z; wcur[3]=a.w;
            wcur[4]=b.x; wcur[5]=b.y; wcur[6]=b.z;
#pragma unroll
            for (int kx = 0; kx < 7; ++kx)
#pragma unroll
                for (int px = 0; px < 22; ++px) {
                    acc[0][px] = fmaf(in[px + kx], wcur[kx], acc[0][px]);
                    acc[1][px] = fmaf(in[px + kx], wprev[kx], acc[1][px]);
                }
#pragma unroll
            for (int k = 0; k < 7; ++k) wprev[k] = wcur[k];
        }

        // ri = 7 (peeled): out row 1, ky = 6
        {
            const float4* rp = reinterpret_cast<const float4*>(s_x + (r0 + 7) * 28);
#pragma unroll
            for (int j = 0; j < 7; ++j) {
                const float4 v = rp[j];
                in[4*j+0] = v.x; in[4*j+1] = v.y; in[4*j+2] = v.z; in[4*j+3] = v.w;
            }
#pragma unroll
            for (int kx = 0; kx < 7; ++kx)
#pragma unroll
                for (int px = 0; px < 22; ++px)
                    acc[1][px] = fmaf(in[px + kx], wprev[kx], acc[1][px]);
        }

        // epilogue: relu -> s_h (48 floats incl zero pads, 12 aligned f4);
        //           ratio1 -> out (44 floats contiguous, 11 aligned f4)
        float h[2][22], r[2][22];
#pragma unroll
        for (int o = 0; o < 2; ++o)
#pragma unroll
            for (int px = 0; px < 22; ++px) {
                const float v = acc[o][px];
                h[o][px] = v > 0.0f ? v : 0.0f;
                r[o][px] = v > 0.0f ? 1.0f : 0.0f;
            }
        float4* hd = reinterpret_cast<float4*>(s_h + oc * 532 + r0 * 24);
#pragma unroll
        for (int j = 0; j < 5; ++j)
            hd[j] = make_float4(h[0][4*j], h[0][4*j+1], h[0][4*j+2], h[0][4*j+3]);
        hd[5] = make_float4(h[0][20], h[0][21], 0.0f, 0.0f);
#pragma unroll
        for (int j = 0; j < 5; ++j)
            hd[6 + j] = make_float4(h[1][4*j], h[1][4*j+1], h[1][4*j+2], h[1][4*j+3]);
        hd[11] = make_float4(h[1][20], h[1][21], 0.0f, 0.0f);

        float4* rp1 = reinterpret_cast<float4*>(out + r1_base + oc * 484 + r0 * 22);
#pragma unroll
        for (int j = 0; j < 11; ++j) {
            const int base = 4 * j;   // 0..43 over concatenated 2 rows
            float v[4];
#pragma unroll
            for (int q = 0; q < 4; ++q) {
                const int idx = base + q;
                v[q] = (idx < 22) ? r[0][idx] : r[1][idx - 22];
            }
            rp1[j] = make_float4(v[0], v[1], v[2], v[3]);
        }
    }
    __syncthreads();

    // ---- conv2: task = (rowtriple g 0..5, oc 0..9), 60 tasks on wave 0 ----
    if (tid < 64) {
        const int t  = tid < 60 ? tid : 59;
        const int g  = t / 10;
        const int oc = t - g * 10;
        const int r0 = 3 * g;

        float acc[3][18];
#pragma unroll
        for (int o = 0; o < 3; ++o)
#pragma unroll
            for (int px = 0; px < 18; ++px) acc[o][px] = 0.0f;

#pragma unroll 1
        for (int ic = 0; ic < 10; ++ic) {
            float w[28];
            const float4* wp = reinterpret_cast<const float4*>(s_wb + oc * 280 + ic * 28);
#pragma unroll
            for (int j = 0; j < 7; ++j) {
                const float4 v = wp[j];
                w[4*j+0] = v.x; w[4*j+1] = v.y; w[4*j+2] = v.z; w[4*j+3] = v.w;
            }
            const float* hb = s_h + ic * 532 + r0 * 24;
#pragma unroll
            for (int ri = 0; ri < 7; ++ri) {
                float in[24];
                const float4* rp = reinterpret_cast<const float4*>(hb + ri * 24);
#pragma unroll
                for (int j = 0; j < 6; ++j) {
                    const float4 v = rp[j];
                    in[4*j+0] = v.x; in[4*j+1] = v.y; in[4*j+2] = v.z; in[4*j+3] = v.w;
                }
#pragma unroll
                for (int o = 0; o < 3; ++o) {
                    const int ky = ri - o;
                    if (ky >= 0 && ky <= 4) {
#pragma unroll
                        for (int kx = 0; kx < 5; ++kx)
#pragma unroll
                            for (int px = 0; px < 18; ++px)
                                acc[o][px] = fmaf(in[px + kx], w[ky * 5 + kx], acc[o][px]);
                    }
                }
            }
        }

        // epilogue: 54 contiguous floats per output; 27 aligned float2 each
        float hv[54], rv[54];
#pragma unroll
        for (int o = 0; o < 3; ++o)
#pragma unroll
            for (int px = 0; px < 18; ++px) {
                const float v = acc[o][px];
                hv[o * 18 + px] = v > 0.0f ? v : 0.0f;
                rv[o * 18 + px] = v > 0.0f ? 1.0f : 0.0f;
            }
        float2* h2p = reinterpret_cast<float2*>(out + h2_base + oc * 324 + r0 * 18);
        float2* r2p = reinterpret_cast<float2*>(out + r2_base + oc * 324 + r0 * 18);
#pragma unroll
        for (int j = 0; j < 27; ++j) {
            h2p[j] = make_float2(hv[2*j], hv[2*j+1]);
            r2p[j] = make_float2(rv[2*j], rv[2*j+1]);
        }
    }
}

extern "C" void kernel_launch(void* const* d_in, const int* in_sizes, int n_in,
                              void* d_out, int out_size, void* d_ws, size_t ws_size,
                              hipStream_t stream) {
    const float* x  = (const float*)d_in[0];
    const float* Wa = (const float*)d_in[1];
    const float* Wb = (const float*)d_in[2];
    float* out = (float*)d_out;
    const int nimg = in_sizes[0] / 784;

    brewcnn_v7<<<nimg, THREADS, 0, stream>>>(x, Wa, Wb, out, nimg);
}